// Round 13
// baseline (974.928 us; speedup 1.0000x reference)
//
#include <hip/hip_runtime.h>
#include <stdint.h>
#include <stddef.h>

using u16 = unsigned short;
using u32 = unsigned int;
using u64 = unsigned long long;

typedef __attribute__((ext_vector_type(8))) short short8;
typedef __attribute__((ext_vector_type(4))) float f32x4;

#define DEV static __device__ __forceinline__

DEV float bf2f(u16 v){ union{u32 u; float f;} x; x.u = ((u32)v)<<16; return x.f; }
DEV u16 f2bf(float f){ union{float f; u32 u;} x; x.f = f; u32 r = (x.u + 0x7FFFu + ((x.u>>16)&1u))>>16; return (u16)r; }
DEV float lo16(u32 u){ union{u32 u; float f;} x; x.u = u<<16; return x.f; }
DEV float hi16(u32 u){ union{u32 u; float f;} x; x.u = u & 0xFFFF0000u; return x.f; }

DEV void gload16(const u16* g, u16* l){
  __builtin_amdgcn_global_load_lds((const __attribute__((address_space(1))) void*)g,
                                   (__attribute__((address_space(3))) void*)l, 16, 0, 0);
}

#define BAR    __builtin_amdgcn_s_barrier()
#define SCHED0 __builtin_amdgcn_sched_barrier(0)
#define PRIO1  __builtin_amdgcn_s_setprio(1)
#define PRIO0  __builtin_amdgcn_s_setprio(0)
#define VMC4   asm volatile("s_waitcnt vmcnt(4)" ::: "memory")
#define VMC0   asm volatile("s_waitcnt vmcnt(0)" ::: "memory")

// ---------------------------------------------------------------------------
// conv 3x3 as implicit GEMM, 256x256 tile, BK=64, 8 waves (2M x 4N).
// R13: single-region K-tile with SEPARATE aR0/aR1 register sets. R8's
// single-barrier failed (650us) because shared aR created a register WAR
// that pinned the m1 reads behind Q01's MFMA issue. With 24 distinct frag
// regs, ALL ds_reads issue first; compiler's partial lgkmcnt (m97-verified)
// lands reads 13..24 on the LDS pipe UNDER Q00/Q01 on the matrix pipe.
// Stages -> alt at loop top; one vmcnt(0) a full K-tile later (free).
// Cycle model: LDS 2304 || MFMA 2483 per K-tile/CU -> floor ~3060 cyc.
// Fused epilogue: bn1+relu -> O, plus Cvec/Hvec/Wvec partial reductions.
// ---------------------------------------------------------------------------
__global__ __launch_bounds__(512, 2)
void conv_gemm256(const u16* __restrict__ xp, const u16* __restrict__ wt,
                  u16* __restrict__ O, const float* __restrict__ sb,
                  float* __restrict__ Cvec, float* __restrict__ Hvec,
                  float* __restrict__ Wvec)
{
  constexpr int NT = 288;   // 9 taps * 2048 / 64
  __shared__ u16 smA[2*256*64];
  __shared__ u16 smB[2*256*64];
  const int t = threadIdx.x;
  const int lane = t & 63;
  const int wv = t >> 6;
  const int wr = wv >> 2, wc = wv & 3;
  const int mt = blockIdx.x, nt = blockIdx.y, b = blockIdx.z;
  const int ij0 = mt*256, n0 = nt*256;
  const u16* Ab = xp + (size_t)b*66*66*2048;

  const int tA   = t >> 3;                       // 0..63
  const int sc8  = ((t&7) ^ ((t>>3)&7)) * 8;     // pre-swizzled source chunk
  const int ldsc = (t&7) * 8;                    // linear LDS chunk
  const int qB   = t >> 8;                       // 0..1
  const int rB   = (t>>3) & 31;                  // 0..31

  f32x4 acc[8][4];
  #pragma unroll
  for (int i=0;i<8;++i)
    #pragma unroll
    for (int j=0;j<4;++j) acc[i][j] = (f32x4){0.f,0.f,0.f,0.f};

  short8 aR0[4][2];     // m-half 0 fragments
  short8 aR1[4][2];     // m-half 1 fragments (separate regs -> no WAR)
  short8 bR[2][2][2];   // [nh][ni][kk]

#define STG_A(dst, s, kt_) do{ \
    const int ktc = (kt_) < NT ? (kt_) : (NT-1); \
    const int tap = ktc>>5; const int ty = (tap*11)>>5; const int tx = tap - ty*3; \
    const size_t ko = ((size_t)(ktc&31))<<6; \
    _Pragma("unroll") for (int l=0;l<2;++l){ \
      const int row = (s)*64 + tA + l*128; \
      const u16* src = Ab + ((size_t)((mt*4 + (s) + l*2 + ty)*66 + tA + tx))*2048 + ko + sc8; \
      gload16(src, (dst) + row*64 + ldsc); } }while(0)

#define STG_B(dst, s, kt_) do{ \
    const int ktc = (kt_) < NT ? (kt_) : (NT-1); \
    const int tap = ktc>>5; \
    const size_t ko = (size_t)tap*2048 + (((size_t)(ktc&31))<<6); \
    _Pragma("unroll") for (int l=0;l<2;++l){ \
      const int row = (l*2 + qB)*64 + (s)*32 + rB; \
      const u16* src = wt + ((size_t)(n0 + row))*9*2048 + ko + sc8; \
      gload16(src, (dst) + row*64 + ldsc); } }while(0)

#define LDA_(arr, base, mh) do{ _Pragma("unroll") for(int mi=0;mi<4;++mi){ \
    const int r = wr*128 + (mh)*64 + mi*16 + (lane&15); \
    _Pragma("unroll") for(int kk=0;kk<2;++kk){ \
      const int ch = (kk*4 + (lane>>4)) ^ (r&7); \
      arr[mi][kk] = *(const short8*)&(base)[r*64 + ch*8]; } } }while(0)
#define LDB_(base, nh) do{ _Pragma("unroll") for(int ni=0;ni<2;++ni){ \
    const int r = wc*64 + (nh)*32 + ni*16 + (lane&15); \
    _Pragma("unroll") for(int kk=0;kk<2;++kk){ \
      const int ch = (kk*4 + (lane>>4)) ^ (r&7); \
      bR[nh][ni][kk] = *(const short8*)&(base)[r*64 + ch*8]; } } }while(0)
#define MFMAQ(arr, mh, nh) do{ _Pragma("unroll") for(int mi=0;mi<4;++mi) \
    _Pragma("unroll") for(int ni=0;ni<2;++ni){ \
      acc[(mh)*4+mi][(nh)*2+ni] = __builtin_amdgcn_mfma_f32_16x16x32_bf16(arr[mi][0], bR[nh][ni][0], acc[(mh)*4+mi][(nh)*2+ni],0,0,0); \
      acc[(mh)*4+mi][(nh)*2+ni] = __builtin_amdgcn_mfma_f32_16x16x32_bf16(arr[mi][1], bR[nh][ni][1], acc[(mh)*4+mi][(nh)*2+ni],0,0,0); } }while(0)

  // prologue: stage all 4 stripes of K-tile 0; drain fully (reads touch all)
  STG_A(smA, 0, 0);
  STG_B(smB, 0, 0);
  STG_B(smB, 1, 0);
  STG_A(smA, 1, 0);
  VMC0;
  BAR;

  for (int j=0; j<NT; ++j) {
    const int p = j & 1;
    const u16* As = smA + (p<<14);
    const u16* Bs = smB + (p<<14);
    u16* Aalt = smA + ((p^1)<<14);
    u16* Balt = smB + ((p^1)<<14);

    // stage K-tile j+1 -> alt (issued first; drained a full K-tile later)
    STG_A(Aalt, 0, j+1);
    STG_B(Balt, 0, j+1);
    STG_B(Balt, 1, j+1);
    STG_A(Aalt, 1, j+1);

    // ALL 24 ds_reads up front, in quadrant-consumption order:
    // Q00 needs aR0+bR[0] (first 12), Q01 +bR[1] (16), Q10/Q11 +aR1 (24).
    LDA_(aR0, As, 0);
    LDB_(Bs, 0);
    LDB_(Bs, 1);
    LDA_(aR1, As, 1);

    PRIO1;
    MFMAQ(aR0, 0, 0);
    MFMAQ(aR0, 0, 1);
    MFMAQ(aR1, 1, 0);
    MFMAQ(aR1, 1, 1);
    PRIO0;

    VMC0;   // tile j+1's 8 stages landed (oldest issued ~3000 cyc ago)
    BAR;    // publish alt; cur fully consumed -> free for overwrite
  }

  // ---- fused epilogue: bn1+relu -> O, plus Cvec/Hvec/Wvec partials ----
  BAR;
  float* red = (float*)smA;   // [0..255] col sums, [256..319] x sums, [320..323] y sums
  if (t < 324) red[t] = 0.f;
  BAR;

  float xs[4][4];
  #pragma unroll
  for (int q=0;q<4;++q)
    #pragma unroll
    for (int j2=0;j2<4;++j2) xs[q][j2] = 0.f;
  float ys0 = 0.f, ys1 = 0.f;

  #pragma unroll
  for (int n=0; n<4; ++n) {
    const int cloc = wc*64 + (n>>1)*32 + (n&1)*16 + (lane&15);
    const int col = n0 + cloc;
    const float s = sb[col], bb = sb[512+col];
    float cs = 0.f;
    #pragma unroll
    for (int a=0; a<8; ++a) {
      const int row0 = ij0 + wr*128 + (a>>2)*64 + (a&3)*16 + ((lane>>4)<<2);
      #pragma unroll
      for (int j2=0; j2<4; ++j2) {
        const size_t idx = ((size_t)(b*4096 + row0 + j2))*512 + col;
        float v = acc[a][n][j2]*s + bb;
        v = v > 0.f ? v : 0.f;
        O[idx] = f2bf(v);
        cs += v;
        xs[a&3][j2] += v;
        if (a < 4) ys0 += v; else ys1 += v;
      }
    }
    atomicAdd(&red[cloc], cs);
  }
  #pragma unroll
  for (int off=1; off<16; off<<=1)
    #pragma unroll
    for (int q=0;q<4;++q)
      #pragma unroll
      for (int j2=0;j2<4;++j2) xs[q][j2] += __shfl_xor(xs[q][j2], off);
  if ((lane & 15) == 0) {
    #pragma unroll
    for (int q=0;q<4;++q)
      #pragma unroll
      for (int j2=0;j2<4;++j2)
        atomicAdd(&red[256 + q*16 + (lane>>4)*4 + j2], xs[q][j2]);
  }
  #pragma unroll
  for (int off=1; off<64; off<<=1) { ys0 += __shfl_xor(ys0, off); ys1 += __shfl_xor(ys1, off); }
  if (lane == 0) {
    atomicAdd(&red[320 + wr*2 + 0], ys0);
    atomicAdd(&red[320 + wr*2 + 1], ys1);
  }
  BAR;
  if (t < 256)       atomicAdd(&Cvec[b*512 + n0 + t], red[t]*(1.0f/4096.0f));
  else if (t < 320)  atomicAdd(&Hvec[b*64 + (t-256)], red[t]*(1.0f/32768.0f));
  else if (t < 324)  atomicAdd(&Wvec[b*64 + (ij0>>6) + (t-320)], red[t]*(1.0f/32768.0f));
#undef STG_A
#undef STG_B
#undef LDA_
#undef LDB_
#undef MFMAQ
}

// ---------------------------------------------------------------------------
// gemm256<V>: R7-verified 4-phase 256x256 loop, plain-GEMM addressing.
// V1: enc (epi bn2+relu col-reduce -> atomic en); V3: fusion (bn3+relu -> O);
// V4: c6a (2 K-segments {outs,c6a1} then {feat,w2b[b]}; bn4+relu -> O).
// ---------------------------------------------------------------------------
template<int V>
__global__ __launch_bounds__(512, 2)
void gemm256(const u16* __restrict__ A0, const u16* __restrict__ A1,
             const u16* __restrict__ Bw0, const u16* __restrict__ Bw1,
             u16* __restrict__ O, const float* __restrict__ sb,
             float* __restrict__ en)
{
  constexpr int NTALL = (V==4) ? 16 : 8;
  __shared__ u16 smA[2*256*64];
  __shared__ u16 smB[2*256*64];
  const int t = threadIdx.x;
  const int lane = t & 63;
  const int wv = t >> 6;
  const int wr = wv >> 2, wc = wv & 3;
  const int mt = blockIdx.x, nt = blockIdx.y, b = blockIdx.z;
  const int ij0 = mt*256, n0 = nt*256;
  const u16* A0b = A0 + (size_t)b*4096*512;
  const u16* A1b = (V==4) ? (A1 + (size_t)b*4096*512) : nullptr;
  const u16* B1b = (V==4) ? (Bw1 + (size_t)b*512*512) : nullptr;

  const int tA   = t >> 3;
  const int sc8  = ((t&7) ^ ((t>>3)&7)) * 8;
  const int ldsc = (t&7) * 8;
  const int qB   = t >> 8;
  const int rB   = (t>>3) & 31;

  f32x4 acc[8][4];
  #pragma unroll
  for (int i=0;i<8;++i)
    #pragma unroll
    for (int j=0;j<4;++j) acc[i][j] = (f32x4){0.f,0.f,0.f,0.f};

  short8 aR[4][2];
  short8 bR[2][2][2];

#define STG_A(dst, s, kt_) do{ \
    const int ktc = (kt_) < NTALL ? (kt_) : (NTALL-1); \
    const u16* Abase = (V==4 && ktc>=8) ? A1b : A0b; \
    const size_t ko = ((size_t)(ktc&7))<<6; \
    _Pragma("unroll") for (int l=0;l<2;++l){ \
      const int row = (s)*64 + tA + l*128; \
      const u16* src = Abase + (size_t)(ij0 + row)*512 + ko + sc8; \
      gload16(src, (dst) + row*64 + ldsc); } }while(0)

#define STG_B(dst, s, kt_) do{ \
    const int ktc = (kt_) < NTALL ? (kt_) : (NTALL-1); \
    const u16* Bbase = (V==4 && ktc>=8) ? B1b : Bw0; \
    const size_t ko = ((size_t)(ktc&7))<<6; \
    _Pragma("unroll") for (int l=0;l<2;++l){ \
      const int row = (l*2 + qB)*64 + (s)*32 + rB; \
      const u16* src = Bbase + (size_t)(n0 + row)*512 + ko + sc8; \
      gload16(src, (dst) + row*64 + ldsc); } }while(0)

#define LDA_(base, mh) do{ _Pragma("unroll") for(int mi=0;mi<4;++mi){ \
    const int r = wr*128 + (mh)*64 + mi*16 + (lane&15); \
    _Pragma("unroll") for(int kk=0;kk<2;++kk){ \
      const int ch = (kk*4 + (lane>>4)) ^ (r&7); \
      aR[mi][kk] = *(const short8*)&(base)[r*64 + ch*8]; } } }while(0)
#define LDB_(base, nh) do{ _Pragma("unroll") for(int ni=0;ni<2;++ni){ \
    const int r = wc*64 + (nh)*32 + ni*16 + (lane&15); \
    _Pragma("unroll") for(int kk=0;kk<2;++kk){ \
      const int ch = (kk*4 + (lane>>4)) ^ (r&7); \
      bR[nh][ni][kk] = *(const short8*)&(base)[r*64 + ch*8]; } } }while(0)
#define MFMAQ(mh, nh) do{ _Pragma("unroll") for(int mi=0;mi<4;++mi) \
    _Pragma("unroll") for(int ni=0;ni<2;++ni){ \
      acc[(mh)*4+mi][(nh)*2+ni] = __builtin_amdgcn_mfma_f32_16x16x32_bf16(aR[mi][0], bR[nh][ni][0], acc[(mh)*4+mi][(nh)*2+ni],0,0,0); \
      acc[(mh)*4+mi][(nh)*2+ni] = __builtin_amdgcn_mfma_f32_16x16x32_bf16(aR[mi][1], bR[nh][ni][1], acc[(mh)*4+mi][(nh)*2+ni],0,0,0); } }while(0)

  STG_A(smA, 0, 0);
  STG_B(smB, 0, 0);
  STG_B(smB, 1, 0);
  STG_A(smA, 1, 0);
  VMC4;
  BAR; SCHED0;

  for (int j=0; j<NTALL; ++j) {
    const int p = j & 1;
    const u16* As = smA + (p<<14);
    const u16* Bs = smB + (p<<14);
    u16* Aalt = smA + ((p^1)<<14);
    u16* Balt = smB + ((p^1)<<14);

    LDA_(As, 0); LDB_(Bs, 0);
    STG_A(Aalt, 0, j+1);
    BAR; SCHED0;
    PRIO1; MFMAQ(0,0); PRIO0;
    VMC4;
    BAR; SCHED0;

    LDB_(Bs, 1);
    STG_B(Balt, 0, j+1);
    BAR; SCHED0;
    PRIO1; MFMAQ(0,1); PRIO0;
    VMC4;
    BAR; SCHED0;

    LDA_(As, 1);
    STG_B(Balt, 1, j+1);
    BAR; SCHED0;
    PRIO1; MFMAQ(1,0); PRIO0;
    BAR; SCHED0;

    STG_A(Aalt, 1, j+1);
    BAR; SCHED0;
    PRIO1; MFMAQ(1,1); PRIO0;
    VMC4;
    BAR; SCHED0;
  }
  VMC0;

  if constexpr (V==1) {
    #pragma unroll
    for (int n=0; n<4; ++n) {
      const int col = n0 + wc*64 + (n>>1)*32 + (n&1)*16 + (lane&15);
      const float s = sb[col], bb = sb[512+col];
      float cs = 0.f;
      #pragma unroll
      for (int a=0; a<8; ++a) {
        #pragma unroll
        for (int j2=0; j2<4; ++j2) {
          float v = acc[a][n][j2]*s + bb;
          cs += (v > 0.f) ? v : 0.f;
        }
      }
      cs += __shfl_xor(cs, 16);
      cs += __shfl_xor(cs, 32);
      if (lane < 16) atomicAdd(&en[b*512 + col], cs * (1.0f/4096.0f));
    }
  } else {
    #pragma unroll
    for (int n=0; n<4; ++n) {
      const int col = n0 + wc*64 + (n>>1)*32 + (n&1)*16 + (lane&15);
      const float s = sb[col], bb = sb[512+col];
      #pragma unroll
      for (int a=0; a<8; ++a) {
        const int row0 = ij0 + wr*128 + (a>>2)*64 + (a&3)*16 + ((lane>>4)<<2);
        #pragma unroll
        for (int j2=0; j2<4; ++j2) {
          const size_t idx = ((size_t)(b*4096 + row0 + j2))*512 + col;
          float v = acc[a][n][j2]*s + bb;
          O[idx] = f2bf(v > 0.f ? v : 0.f);
        }
      }
    }
  }
#undef STG_A
#undef STG_B
#undef LDA_
#undef LDB_
#undef MFMAQ
}

// ---------------------------------------------------------------------------
// 128x128 tile GEMM (V2 only): t1 K=128, B per-batch CCT; epi O = feat*(1+acc).
// ---------------------------------------------------------------------------
template<int V>
__global__ __launch_bounds__(256)
void gemm128(const u16* __restrict__ A, const u16* __restrict__ Bw, u16* __restrict__ O,
             const u16* __restrict__ feat, const u16* __restrict__ B2,
             const float* __restrict__ sb, float* __restrict__ en)
{
  constexpr int KSEG = 128;
  __shared__ u16 smA[128*64];
  __shared__ u16 smB[128*64];
  const int tid = threadIdx.x;
  const int lane = tid & 63;
  const int wv = tid >> 6;
  const int wr = wv >> 1, wc = wv & 1;
  const int mt = blockIdx.x, nt = blockIdx.y, b = blockIdx.z;
  const int ij0 = mt*128, n0 = nt*128;
  const int srow = tid >> 3, schunk = tid & 7;

  f32x4 acc[4][4];
  #pragma unroll
  for (int i=0;i<4;++i)
    #pragma unroll
    for (int j=0;j<4;++j) acc[i][j] = (f32x4){0.f,0.f,0.f,0.f};

  const u16* Ab = A + (size_t)b*4096*128;
  const u16* Bb = Bw + (size_t)b*512*128;

  for (int kt=0; kt<KSEG/64; ++kt) {
    const int k0 = kt*64;
    #pragma unroll
    for (int i=0;i<4;++i) {
      const int row = i*32 + srow;
      const int sc = schunk ^ (row & 7);
      gload16(Ab + (size_t)(ij0+row)*128 + (k0 + sc*8), &smA[row*64 + schunk*8]);
    }
    #pragma unroll
    for (int i=0;i<4;++i) {
      const int row = i*32 + srow;
      const int sc = schunk ^ (row & 7);
      gload16(Bb + (size_t)(n0+row)*128 + (k0 + sc*8), &smB[row*64 + schunk*8]);
    }
    __syncthreads();
    #pragma unroll
    for (int ks=0; ks<2; ++ks) {
      short8 av[4], bv[4];
      #pragma unroll
      for (int mi=0;mi<4;++mi) {
        const int r = wr*64 + mi*16 + (lane & 15);
        const int ch = (ks*4 + (lane>>4)) ^ (r & 7);
        av[mi] = *(const short8*)&smA[r*64 + ch*8];
      }
      #pragma unroll
      for (int ni=0;ni<4;++ni) {
        const int r = wc*64 + ni*16 + (lane & 15);
        const int ch = (ks*4 + (lane>>4)) ^ (r & 7);
        bv[ni] = *(const short8*)&smB[r*64 + ch*8];
      }
      #pragma unroll
      for (int mi=0;mi<4;++mi)
        #pragma unroll
        for (int ni=0;ni<4;++ni)
          acc[mi][ni] = __builtin_amdgcn_mfma_f32_16x16x32_bf16(av[mi], bv[ni], acc[mi][ni], 0, 0, 0);
    }
    __syncthreads();
  }

  #pragma unroll
  for (int ni=0;ni<4;++ni) {
    const int col = n0 + wc*64 + ni*16 + (lane & 15);
    #pragma unroll
    for (int mi=0;mi<4;++mi) {
      const int row0 = ij0 + wr*64 + mi*16 + ((lane>>4)<<2);
      #pragma unroll
      for (int j=0;j<4;++j) {
        const size_t idx = ((size_t)(b*4096 + row0 + j))*512 + col;
        O[idx] = f2bf(bf2f(feat[idx]) * (1.0f + acc[mi][ni][j]));
      }
    }
  }
}

// ---------------------------------------------------------------------------
// Weight prep + bn fold (coalesced wt-transpose via LDS slab).
// ---------------------------------------------------------------------------
__global__ __launch_bounds__(256)
void prep_weights(const float* __restrict__ fw, const float* __restrict__ encw,
                  const float* __restrict__ fusw, const float* __restrict__ c6aw,
                  const float* g1,const float* b1,const float* m1,const float* v1,
                  const float* g2,const float* b2,const float* m2,const float* v2,
                  const float* g3,const float* b3,const float* m3,const float* v3,
                  const float* g4,const float* b4,const float* m4,const float* v4,
                  u16* __restrict__ wt, u16* __restrict__ encb,
                  u16* __restrict__ fusb, u16* __restrict__ c6a1,
                  float* __restrict__ bnsb)
{
  const int bx = blockIdx.x, t = threadIdx.x;
  if (bx < 512) {
    __shared__ float slab[2048*9];
    const int o = bx;
    const float4* src4 = (const float4*)(fw + (size_t)o*2048*9);
    float4* slab4 = (float4*)slab;
    #pragma unroll
    for (int i=0; i<18; ++i) slab4[i*256 + t] = src4[i*256 + t];
    __syncthreads();
    #pragma unroll
    for (int tt=0; tt<9; ++tt) {
      #pragma unroll
      for (int i=0; i<8; ++i) {
        const int c = i*256 + t;
        wt[((size_t)o*9 + tt)*2048 + c] = f2bf(slab[c*9 + tt]);
      }
    }
  } else if (bx < 1536) {
    const int i = (bx-512)*256 + t;
    encb[i] = f2bf(encw[i]);
  } else if (bx < 2560) {
    const int i = (bx-1536)*256 + t;
    fusb[i] = f2bf(fusw[i]);
  } else if (bx < 3584) {
    const int i = (bx-2560)*256 + t;
    c6a1[i] = f2bf(c6aw[(size_t)(i>>9)*1024 + (i&511)]);
  } else {
    const int c = (bx-3584)*256 + t;
    if (c < 512) {
      const float eps = 1e-5f;
      float s1 = g1[c]*rsqrtf(v1[c]+eps); bnsb[c]      = s1; bnsb[512+c]  = b1[c]-m1[c]*s1;
      float s2 = g2[c]*rsqrtf(v2[c]+eps); bnsb[1024+c] = s2; bnsb[1536+c] = b2[c]-m2[c]*s2;
      float s3 = g3[c]*rsqrtf(v3[c]+eps); bnsb[2048+c] = s3; bnsb[2560+c] = b3[c]-m3[c]*s3;
      float s4 = g4[c]*rsqrtf(v4[c]+eps); bnsb[3072+c] = s4; bnsb[3584+c] = b4[c]-m4[c]*s4;
    }
  }
}

// x [8][2048][64][64] f32 -> xp [8][66][66][2048] bf16 (zero pad). float4 reads.
__global__ __launch_bounds__(256)
void pad_x(const float* __restrict__ x, u16* __restrict__ xp)
{
  __shared__ u16 tile[256*68];
  const int bx = blockIdx.x;
  const int cb = bx & 7, y = (bx>>3) & 63, b = bx >> 9;
  const int t = threadIdx.x;
  const int xg = t & 15, crow = t >> 4;
  for (int it=0; it<16; ++it) {
    const int cl = it*16 + crow;
    const float4 v = *(const float4*)&x[(((size_t)b*2048 + cb*256 + cl)*64 + y)*64 + xg*4];
    const u64 pk = (u64)f2bf(v.x) | ((u64)f2bf(v.y)<<16) | ((u64)f2bf(v.z)<<32) | ((u64)f2bf(v.w)<<48);
    *(u64*)&tile[cl*68 + xg*4] = pk;
  }
  __syncthreads();
  const size_t rowbase = (size_t)(b*66 + y + 1)*66;
  for (int px=0; px<64; ++px)
    xp[(rowbase + px + 1)*2048 + cb*256 + t] = tile[t*68 + px];
  xp[rowbase*2048 + cb*256 + t] = 0;
  xp[(rowbase + 65)*2048 + cb*256 + t] = 0;
  if (y == 0) {
    const size_t rb = (size_t)(b*66)*66;
    for (int px=0; px<66; ++px) xp[(rb+px)*2048 + cb*256 + t] = 0;
  }
  if (y == 63) {
    const size_t rb = (size_t)(b*66 + 65)*66;
    for (int px=0; px<66; ++px) xp[(rb+px)*2048 + cb*256 + t] = 0;
  }
}

// gamma (8 blk), HH/WW (128 blk), CCT (512 blk x 128 o)
__global__ __launch_bounds__(256)
void small1(const float* __restrict__ en, const float* __restrict__ fcw, const float* __restrict__ fcb,
            const float* __restrict__ w1, const float* __restrict__ Cvec,
            const float* __restrict__ w2, const float* __restrict__ w3,
            const float* __restrict__ Hvec, const float* __restrict__ Wvec,
            float* __restrict__ gamma, u16* __restrict__ CCT,
            float* __restrict__ HH, float* __restrict__ WW)
{
  const int bx = blockIdx.x, t = threadIdx.x;
  if (bx < 8) {
    __shared__ float enl[512];
    const int b = bx;
    for (int c=t;c<512;c+=256) enl[c] = en[b*512+c];
    __syncthreads();
    for (int o=t;o<512;o+=256) {
      float a = fcb[o];
      const float* wr = fcw + (size_t)o*512;
      for (int c=0;c<512;++c) a += enl[c]*wr[c];
      gamma[b*512+o] = 1.0f/(1.0f+__expf(-a));
    }
  } else if (bx < 136) {
    __shared__ float hl[512], wl[512];
    const int r = bx - 8;
    for (int i=t;i<512;i+=256){ hl[i]=Hvec[i]; wl[i]=Wvec[i]; }
    __syncthreads();
    const int i = t & 63, bh = t >> 6;
    for (int bb=bh; bb<8; bb+=4) {
      float sh=0.f, sw=0.f;
      const float* w2r = w2 + ((size_t)r*64 + i)*64;
      const float* w3r = w3 + ((size_t)r*64 + i)*64;
      #pragma unroll 8
      for (int h=0;h<64;++h){ sh += w2r[h]*hl[bb*64+h]; sw += w3r[h]*wl[bb*64+h]; }
      HH[((size_t)bb*128 + r)*64 + i] = 1.0f/(1.0f+__expf(-sh));
      WW[((size_t)bb*128 + r)*64 + i] = 1.0f/(1.0f+__expf(-sw));
    }
  } else {
    __shared__ float cv[4096];
    for (int i=t;i<4096;i+=256) cv[i] = Cvec[i];
    __syncthreads();
    const int rr    = (bx-136) >> 2;           // r in [0,128)
    const int obase = ((bx-136) & 3) * 128;    // o quarter
    const int lane = t & 63, wg = t >> 6;
    const float* w1r = w1 + (size_t)rr*512*512;
    for (int i=0; i<32; ++i) {
      const int o = obase + wg*32 + i;
      const float* row = w1r + (size_t)o*512;
      const float4 wA = *(const float4*)(row + lane*8);
      const float4 wB = *(const float4*)(row + lane*8 + 4);
      float ab[8];
      #pragma unroll
      for (int bb=0;bb<8;++bb) {
        const float4 cA = *(const float4*)&cv[bb*512 + lane*8];
        const float4 cB = *(const float4*)&cv[bb*512 + lane*8 + 4];
        ab[bb] = wA.x*cA.x + wA.y*cA.y + wA.z*cA.z + wA.w*cA.w
               + wB.x*cB.x + wB.y*cB.y + wB.z*cB.z + wB.w*cB.w;
      }
      #pragma unroll
      for (int off=32; off; off>>=1)
        #pragma unroll
        for (int bb=0;bb<8;++bb) ab[bb] += __shfl_xor(ab[bb], off);
      #pragma unroll
      for (int bb=0;bb<8;++bb)
        if (lane == bb)
          CCT[((size_t)bb*512 + o)*128 + rr] = f2bf((1.0f/(1.0f+__expf(-ab[bb]))) * 0.015625f);
    }
  }
}

// w2b[b][o][c] = c6a_w[o][512+c]*(1+gamma[b][c]) bf16 ; HWT[b][ij][r] = HH[b][r][y]*WW[b][r][x]
__global__ __launch_bounds__(256)
void small2(const float* __restrict__ c6aw, const float* __restrict__ gamma,
            const float* __restrict__ HH, const float* __restrict__ WW,
            u16* __restrict__ w2b, u16* __restrict__ HWT)
{
  const int bx = blockIdx.x, t = threadIdx.x;
  if (bx < 4096) {
    const int b = bx >> 9, o = bx & 511;
    const float* src = c6aw + (size_t)o*1024 + 512;
    const float* gmv = gamma + b*512;
    u16* dst = w2b + ((size_t)b*512 + o)*512;
    for (int c=t;c<512;c+=256) dst[c] = f2bf(src[c]*(1.0f+gmv[c]));
  } else {
    __shared__ float wwl[64*129];
    __shared__ float hhy[128];
    const int idx = bx - 4096;
    const int b = idx >> 6, y = idx & 63;
    for (int g=t; g<8192; g+=256){ const int r=g>>6, xx=g&63; wwl[xx*129+r] = WW[((size_t)b*128+r)*64+xx]; }
    if (t < 128) hhy[t] = HH[((size_t)b*128 + t)*64 + y];
    __syncthreads();
    const int r2 = (t & 63)*2, xg = t >> 6;
    for (int xx=xg; xx<64; xx+=4) {
      const float v0 = hhy[r2]   * wwl[xx*129 + r2];
      const float v1 = hhy[r2+1] * wwl[xx*129 + r2 + 1];
      const u32 pk = (u32)f2bf(v0) | ((u32)f2bf(v1)<<16);
      *(u32*)&HWT[((size_t)(b*4096 + y*64 + xx))*128 + r2] = pk;
    }
  }
}

// out[b][o][ij] = sum_c c6b_w[o][c]*h6[b][ij][c] + c6b_b[o]; 2-way c-split.
__global__ __launch_bounds__(256)
void c6b_head(const u16* __restrict__ h6, const float* __restrict__ w,
              const float* __restrict__ bias, float* __restrict__ out)
{
  __shared__ float part[128*21];
  const int t = threadIdx.x;
  const int pl = t & 127, half = t >> 7;
  const int pix = (blockIdx.x << 7) + pl;
  const int b = pix >> 12, ij = pix & 4095;
  float acc[19];
  #pragma unroll
  for (int o=0;o<19;++o) acc[o] = 0.f;
  const u16* hp = h6 + (size_t)pix*512 + half*256;
  const float* wh = w + half*256;
  for (int c0=0;c0<256;c0+=8) {
    const uint4 d = *(const uint4*)(hp + c0);
    const float f0=lo16(d.x),f1=hi16(d.x),f2=lo16(d.y),f3=hi16(d.y),
                f4=lo16(d.z),f5=hi16(d.z),f6=lo16(d.w),f7=hi16(d.w);
    #pragma unroll
    for (int o=0;o<19;++o) {
      const float* wr = wh + o*512 + c0;
      acc[o] += f0*wr[0] + f1*wr[1] + f2*wr[2] + f3*wr[3]
              + f4*wr[4] + f5*wr[5] + f6*wr[6] + f7*wr[7];
    }
  }
  if (half) {
    #pragma unroll
    for (int o=0;o<19;++o) part[pl*21 + o] = acc[o];
  }
  __syncthreads();
  if (!half) {
    #pragma unroll
    for (int o=0;o<19;++o)
      out[((size_t)(b*19 + o))*4096 + ij] = acc[o] + part[pl*21 + o] + bias[o];
  }
}

// ---------------------------------------------------------------------------
extern "C" void kernel_launch(void* const* d_in, const int* in_sizes, int n_in,
                              void* d_out, int out_size, void* d_ws, size_t ws_size,
                              hipStream_t stream)
{
  (void)in_sizes; (void)n_in; (void)out_size;
  const float* x     = (const float*)d_in[0];
  const float* fw    = (const float*)d_in[1];
  const float* bnp[16];
  for (int i=0;i<16;++i) bnp[i] = (const float*)d_in[2+i];
  const float* enc_w = (const float*)d_in[18];
  const float* fc_w  = (const float*)d_in[19];
  const float* fc_b  = (const float*)d_in[20];
  const float* w1    = (const float*)d_in[21];
  const float* w2    = (const float*)d_in[22];
  const float* w3    = (const float*)d_in[23];
  const float* fus_w = (const float*)d_in[24];
  const float* c6a_w = (const float*)d_in[25];
  const float* c6b_w = (const float*)d_in[26];
  const float* c6b_b = (const float*)d_in[27];

  char* ws = (char*)d_ws;
  constexpr size_t OFF_XP=0, OFF_T=0, OFF_OUTS=33554432ull, OFF_H6=67108864ull,
    OFF_WT=142737408ull, OFF_FEAT=161611776ull, OFF_HWT=195166208ull, OFF_W2B=203554816ull,
    OFF_CCT=207749120ull, OFF_ENCB=208797696ull, OFF_FUSB=209321984ull, OFF_C6A1=209846272ull,
    OFF_HH=210370560ull, OFF_WW=210632704ull, OFF_EN=210894848ull, OFF_CV=210911232ull,
    OFF_HV=210927616ull, OFF_WV=210929664ull, OFF_GAMMA=210931712ull, OFF_BNSB=210948096ull,
    NEEDED=210964480ull;
  if (ws_size < NEEDED) return;

  u16* xp    = (u16*)(ws + OFF_XP);
  u16* tb    = (u16*)(ws + OFF_T);
  u16* outs  = (u16*)(ws + OFF_OUTS);
  u16* h6    = (u16*)(ws + OFF_H6);
  u16* wt    = (u16*)(ws + OFF_WT);
  u16* featb = (u16*)(ws + OFF_FEAT);
  u16* hwt   = (u16*)(ws + OFF_HWT);
  u16* w2b   = (u16*)(ws + OFF_W2B);
  u16* cct   = (u16*)(ws + OFF_CCT);
  u16* encb  = (u16*)(ws + OFF_ENCB);
  u16* fusb  = (u16*)(ws + OFF_FUSB);
  u16* c6a1  = (u16*)(ws + OFF_C6A1);
  float* HH  = (float*)(ws + OFF_HH);
  float* WW  = (float*)(ws + OFF_WW);
  float* en  = (float*)(ws + OFF_EN);
  float* Cv  = (float*)(ws + OFF_CV);
  float* Hv  = (float*)(ws + OFF_HV);
  float* Wv  = (float*)(ws + OFF_WV);
  float* gm  = (float*)(ws + OFF_GAMMA);
  float* bnsb= (float*)(ws + OFF_BNSB);

  hipMemsetAsync(ws + OFF_EN, 0, 36864, stream);

  prep_weights<<<3586,256,0,stream>>>(fw, enc_w, fus_w, c6a_w,
      bnp[0],bnp[1],bnp[2],bnp[3], bnp[4],bnp[5],bnp[6],bnp[7],
      bnp[8],bnp[9],bnp[10],bnp[11], bnp[12],bnp[13],bnp[14],bnp[15],
      wt, encb, fusb, c6a1, bnsb);
  pad_x<<<4096,256,0,stream>>>(x, xp);
  conv_gemm256<<<dim3(16,2,8),512,0,stream>>>(xp, wt, featb, bnsb, Cv, Hv, Wv);
  gemm256<1><<<dim3(16,2,8),512,0,stream>>>(featb, nullptr, encb, nullptr, nullptr, bnsb+1024, en);
  small1<<<648,256,0,stream>>>(en, fc_w, fc_b, w1, Cv, w2, w3, Hv, Wv, gm, cct, HH, WW);
  small2<<<4608,256,0,stream>>>(c6a_w, gm, HH, WW, w2b, hwt);
  gemm128<2><<<dim3(32,4,8),256,0,stream>>>(hwt, cct, tb, featb, nullptr, nullptr, nullptr);
  gemm256<3><<<dim3(16,2,8),512,0,stream>>>(tb, nullptr, fusb, nullptr, outs, bnsb+2048, nullptr);
  gemm256<4><<<dim3(16,2,8),512,0,stream>>>(outs, featb, c6a1, w2b, h6, bnsb+3072, nullptr);
  c6b_head<<<256,256,0,stream>>>(h6, c6b_w, c6b_b, (float*)d_out);
}

// Round 15
// 884.541 us; speedup vs baseline: 1.1022x; 1.1022x over previous
//
#include <hip/hip_runtime.h>
#include <stdint.h>
#include <stddef.h>

using u16 = unsigned short;
using u32 = unsigned int;
using u64 = unsigned long long;

typedef __attribute__((ext_vector_type(8))) short short8;
typedef __attribute__((ext_vector_type(4))) float f32x4;

#define DEV static __device__ __forceinline__

DEV float bf2f(u16 v){ union{u32 u; float f;} x; x.u = ((u32)v)<<16; return x.f; }
DEV u16 f2bf(float f){ union{float f; u32 u;} x; x.f = f; u32 r = (x.u + 0x7FFFu + ((x.u>>16)&1u))>>16; return (u16)r; }
DEV float lo16(u32 u){ union{u32 u; float f;} x; x.u = u<<16; return x.f; }
DEV float hi16(u32 u){ union{u32 u; float f;} x; x.u = u & 0xFFFF0000u; return x.f; }

DEV void gload16(const u16* g, u16* l){
  __builtin_amdgcn_global_load_lds((const __attribute__((address_space(1))) void*)g,
                                   (__attribute__((address_space(3))) void*)l, 16, 0, 0);
}

#define BAR    __builtin_amdgcn_s_barrier()
#define SCHED0 __builtin_amdgcn_sched_barrier(0)
#define PRIO1  __builtin_amdgcn_s_setprio(1)
#define PRIO0  __builtin_amdgcn_s_setprio(0)
#define VMC4   asm volatile("s_waitcnt vmcnt(4)" ::: "memory")
#define VMC0   asm volatile("s_waitcnt vmcnt(0)" ::: "memory")

// ---------------------------------------------------------------------------
// conv 3x3 as implicit GEMM, 256x256 tile, BK=64, 8 waves (2M x 4N), 4-phase
// counted-vmcnt schedule. R7-VERIFIED LOCAL OPTIMUM: 585us, MfmaUtil 46%.
// Schedule A/B history (4 falsifications of barrier removal): R6 deep=703,
// R8 single-bar=650, R10 SGB=674, R13 sep-regs=673. AXIS CLOSED.
// Fused epilogue: bn1+relu -> O, plus Cvec/Hvec/Wvec partial reductions.
// ---------------------------------------------------------------------------
__global__ __launch_bounds__(512, 2)
void conv_gemm256(const u16* __restrict__ xp, const u16* __restrict__ wt,
                  u16* __restrict__ O, const float* __restrict__ sb,
                  float* __restrict__ Cvec, float* __restrict__ Hvec,
                  float* __restrict__ Wvec)
{
  constexpr int NT = 288;   // 9 taps * 2048 / 64
  __shared__ u16 smA[2*256*64];
  __shared__ u16 smB[2*256*64];
  const int t = threadIdx.x;
  const int lane = t & 63;
  const int wv = t >> 6;
  const int wr = wv >> 2, wc = wv & 3;
  const int mt = blockIdx.x, nt = blockIdx.y, b = blockIdx.z;
  const int ij0 = mt*256, n0 = nt*256;
  const u16* Ab = xp + (size_t)b*66*66*2048;

  const int tA   = t >> 3;                       // 0..63
  const int sc8  = ((t&7) ^ ((t>>3)&7)) * 8;     // pre-swizzled source chunk
  const int ldsc = (t&7) * 8;                    // linear LDS chunk
  const int qB   = t >> 8;                       // 0..1
  const int rB   = (t>>3) & 31;                  // 0..31

  f32x4 acc[8][4];
  #pragma unroll
  for (int i=0;i<8;++i)
    #pragma unroll
    for (int j=0;j<4;++j) acc[i][j] = (f32x4){0.f,0.f,0.f,0.f};

  short8 aR[4][2];
  short8 bR[2][2][2];   // [nh][ni][kk]

#define STG_A(dst, s, kt_) do{ \
    const int ktc = (kt_) < NT ? (kt_) : (NT-1); \
    const int tap = ktc>>5; const int ty = (tap*11)>>5; const int tx = tap - ty*3; \
    const size_t ko = ((size_t)(ktc&31))<<6; \
    _Pragma("unroll") for (int l=0;l<2;++l){ \
      const int row = (s)*64 + tA + l*128; \
      const u16* src = Ab + ((size_t)((mt*4 + (s) + l*2 + ty)*66 + tA + tx))*2048 + ko + sc8; \
      gload16(src, (dst) + row*64 + ldsc); } }while(0)

#define STG_B(dst, s, kt_) do{ \
    const int ktc = (kt_) < NT ? (kt_) : (NT-1); \
    const int tap = ktc>>5; \
    const size_t ko = (size_t)tap*2048 + (((size_t)(ktc&31))<<6); \
    _Pragma("unroll") for (int l=0;l<2;++l){ \
      const int row = (l*2 + qB)*64 + (s)*32 + rB; \
      const u16* src = wt + ((size_t)(n0 + row))*9*2048 + ko + sc8; \
      gload16(src, (dst) + row*64 + ldsc); } }while(0)

#define LDA_(base, mh) do{ _Pragma("unroll") for(int mi=0;mi<4;++mi){ \
    const int r = wr*128 + (mh)*64 + mi*16 + (lane&15); \
    _Pragma("unroll") for(int kk=0;kk<2;++kk){ \
      const int ch = (kk*4 + (lane>>4)) ^ (r&7); \
      aR[mi][kk] = *(const short8*)&(base)[r*64 + ch*8]; } } }while(0)
#define LDB_(base, nh) do{ _Pragma("unroll") for(int ni=0;ni<2;++ni){ \
    const int r = wc*64 + (nh)*32 + ni*16 + (lane&15); \
    _Pragma("unroll") for(int kk=0;kk<2;++kk){ \
      const int ch = (kk*4 + (lane>>4)) ^ (r&7); \
      bR[nh][ni][kk] = *(const short8*)&(base)[r*64 + ch*8]; } } }while(0)
#define MFMAQ(mh, nh) do{ _Pragma("unroll") for(int mi=0;mi<4;++mi) \
    _Pragma("unroll") for(int ni=0;ni<2;++ni){ \
      acc[(mh)*4+mi][(nh)*2+ni] = __builtin_amdgcn_mfma_f32_16x16x32_bf16(aR[mi][0], bR[nh][ni][0], acc[(mh)*4+mi][(nh)*2+ni],0,0,0); \
      acc[(mh)*4+mi][(nh)*2+ni] = __builtin_amdgcn_mfma_f32_16x16x32_bf16(aR[mi][1], bR[nh][ni][1], acc[(mh)*4+mi][(nh)*2+ni],0,0,0); } }while(0)

  // prologue: stage all 4 stripes of K-tile 0; publish A-S0, B-S0
  STG_A(smA, 0, 0);
  STG_B(smB, 0, 0);
  STG_B(smB, 1, 0);
  STG_A(smA, 1, 0);
  VMC4;
  BAR; SCHED0;

  for (int j=0; j<NT; ++j) {
    const int p = j & 1;
    const u16* As = smA + (p<<14);
    const u16* Bs = smB + (p<<14);
    u16* Aalt = smA + ((p^1)<<14);
    u16* Balt = smB + ((p^1)<<14);

    // phase 1: (m0,n0); stage A-S0(j+1)
    LDA_(As, 0); LDB_(Bs, 0);
    STG_A(Aalt, 0, j+1);
    BAR; SCHED0;
    PRIO1; MFMAQ(0,0); PRIO0;
    VMC4;
    BAR; SCHED0;

    // phase 2: (m0,n1); stage B-S0(j+1)
    LDB_(Bs, 1);
    STG_B(Balt, 0, j+1);
    BAR; SCHED0;
    PRIO1; MFMAQ(0,1); PRIO0;
    VMC4;
    BAR; SCHED0;

    // phase 3: (m1,n0); stage B-S1(j+1)
    LDA_(As, 1);
    STG_B(Balt, 1, j+1);
    BAR; SCHED0;
    PRIO1; MFMAQ(1,0); PRIO0;
    BAR; SCHED0;

    // phase 4: (m1,n1); stage A-S1(j+1)
    STG_A(Aalt, 1, j+1);
    BAR; SCHED0;
    PRIO1; MFMAQ(1,1); PRIO0;
    VMC4;
    BAR; SCHED0;
  }

  // ---- fused epilogue: bn1+relu -> O, plus Cvec/Hvec/Wvec partials ----
  VMC0;
  BAR;
  float* red = (float*)smA;   // [0..255] col sums, [256..319] x sums, [320..323] y sums
  if (t < 324) red[t] = 0.f;
  BAR;

  float xs[4][4];
  #pragma unroll
  for (int q=0;q<4;++q)
    #pragma unroll
    for (int j2=0;j2<4;++j2) xs[q][j2] = 0.f;
  float ys0 = 0.f, ys1 = 0.f;

  #pragma unroll
  for (int n=0; n<4; ++n) {
    const int cloc = wc*64 + (n>>1)*32 + (n&1)*16 + (lane&15);
    const int col = n0 + cloc;
    const float s = sb[col], bb = sb[512+col];
    float cs = 0.f;
    #pragma unroll
    for (int a=0; a<8; ++a) {
      const int row0 = ij0 + wr*128 + (a>>2)*64 + (a&3)*16 + ((lane>>4)<<2);
      #pragma unroll
      for (int j2=0; j2<4; ++j2) {
        const size_t idx = ((size_t)(b*4096 + row0 + j2))*512 + col;
        float v = acc[a][n][j2]*s + bb;
        v = v > 0.f ? v : 0.f;
        O[idx] = f2bf(v);
        cs += v;
        xs[a&3][j2] += v;
        if (a < 4) ys0 += v; else ys1 += v;
      }
    }
    atomicAdd(&red[cloc], cs);
  }
  #pragma unroll
  for (int off=1; off<16; off<<=1)
    #pragma unroll
    for (int q=0;q<4;++q)
      #pragma unroll
      for (int j2=0;j2<4;++j2) xs[q][j2] += __shfl_xor(xs[q][j2], off);
  if ((lane & 15) == 0) {
    #pragma unroll
    for (int q=0;q<4;++q)
      #pragma unroll
      for (int j2=0;j2<4;++j2)
        atomicAdd(&red[256 + q*16 + (lane>>4)*4 + j2], xs[q][j2]);
  }
  #pragma unroll
  for (int off=1; off<64; off<<=1) { ys0 += __shfl_xor(ys0, off); ys1 += __shfl_xor(ys1, off); }
  if (lane == 0) {
    atomicAdd(&red[320 + wr*2 + 0], ys0);
    atomicAdd(&red[320 + wr*2 + 1], ys1);
  }
  BAR;
  if (t < 256)       atomicAdd(&Cvec[b*512 + n0 + t], red[t]*(1.0f/4096.0f));
  else if (t < 320)  atomicAdd(&Hvec[b*64 + (t-256)], red[t]*(1.0f/32768.0f));
  else if (t < 324)  atomicAdd(&Wvec[b*64 + (ij0>>6) + (t-320)], red[t]*(1.0f/32768.0f));
#undef STG_A
#undef STG_B
#undef LDA_
#undef LDB_
#undef MFMAQ
}

// ---------------------------------------------------------------------------
// gemm256<V>: R7-verified 4-phase 256x256 loop, plain-GEMM addressing.
// V1: enc (epi bn2+relu col-reduce -> atomic en); V3: fusion (bn3+relu -> O);
// V4: c6a (2 K-segments {outs,c6a1} then {feat,w2b[b]}; bn4+relu -> O).
// ---------------------------------------------------------------------------
template<int V>
__global__ __launch_bounds__(512, 2)
void gemm256(const u16* __restrict__ A0, const u16* __restrict__ A1,
             const u16* __restrict__ Bw0, const u16* __restrict__ Bw1,
             u16* __restrict__ O, const float* __restrict__ sb,
             float* __restrict__ en)
{
  constexpr int NTALL = (V==4) ? 16 : 8;
  __shared__ u16 smA[2*256*64];
  __shared__ u16 smB[2*256*64];
  const int t = threadIdx.x;
  const int lane = t & 63;
  const int wv = t >> 6;
  const int wr = wv >> 2, wc = wv & 3;
  const int mt = blockIdx.x, nt = blockIdx.y, b = blockIdx.z;
  const int ij0 = mt*256, n0 = nt*256;
  const u16* A0b = A0 + (size_t)b*4096*512;
  const u16* A1b = (V==4) ? (A1 + (size_t)b*4096*512) : nullptr;
  const u16* B1b = (V==4) ? (Bw1 + (size_t)b*512*512) : nullptr;

  const int tA   = t >> 3;
  const int sc8  = ((t&7) ^ ((t>>3)&7)) * 8;
  const int ldsc = (t&7) * 8;
  const int qB   = t >> 8;
  const int rB   = (t>>3) & 31;

  f32x4 acc[8][4];
  #pragma unroll
  for (int i=0;i<8;++i)
    #pragma unroll
    for (int j=0;j<4;++j) acc[i][j] = (f32x4){0.f,0.f,0.f,0.f};

  short8 aR[4][2];
  short8 bR[2][2][2];

#define STG_A(dst, s, kt_) do{ \
    const int ktc = (kt_) < NTALL ? (kt_) : (NTALL-1); \
    const u16* Abase = (V==4 && ktc>=8) ? A1b : A0b; \
    const size_t ko = ((size_t)(ktc&7))<<6; \
    _Pragma("unroll") for (int l=0;l<2;++l){ \
      const int row = (s)*64 + tA + l*128; \
      const u16* src = Abase + (size_t)(ij0 + row)*512 + ko + sc8; \
      gload16(src, (dst) + row*64 + ldsc); } }while(0)

#define STG_B(dst, s, kt_) do{ \
    const int ktc = (kt_) < NTALL ? (kt_) : (NTALL-1); \
    const u16* Bbase = (V==4 && ktc>=8) ? B1b : Bw0; \
    const size_t ko = ((size_t)(ktc&7))<<6; \
    _Pragma("unroll") for (int l=0;l<2;++l){ \
      const int row = (l*2 + qB)*64 + (s)*32 + rB; \
      const u16* src = Bbase + (size_t)(n0 + row)*512 + ko + sc8; \
      gload16(src, (dst) + row*64 + ldsc); } }while(0)

#define LDA_(base, mh) do{ _Pragma("unroll") for(int mi=0;mi<4;++mi){ \
    const int r = wr*128 + (mh)*64 + mi*16 + (lane&15); \
    _Pragma("unroll") for(int kk=0;kk<2;++kk){ \
      const int ch = (kk*4 + (lane>>4)) ^ (r&7); \
      aR[mi][kk] = *(const short8*)&(base)[r*64 + ch*8]; } } }while(0)
#define LDB_(base, nh) do{ _Pragma("unroll") for(int ni=0;ni<2;++ni){ \
    const int r = wc*64 + (nh)*32 + ni*16 + (lane&15); \
    _Pragma("unroll") for(int kk=0;kk<2;++kk){ \
      const int ch = (kk*4 + (lane>>4)) ^ (r&7); \
      bR[nh][ni][kk] = *(const short8*)&(base)[r*64 + ch*8]; } } }while(0)
#define MFMAQ(mh, nh) do{ _Pragma("unroll") for(int mi=0;mi<4;++mi) \
    _Pragma("unroll") for(int ni=0;ni<2;++ni){ \
      acc[(mh)*4+mi][(nh)*2+ni] = __builtin_amdgcn_mfma_f32_16x16x32_bf16(aR[mi][0], bR[nh][ni][0], acc[(mh)*4+mi][(nh)*2+ni],0,0,0); \
      acc[(mh)*4+mi][(nh)*2+ni] = __builtin_amdgcn_mfma_f32_16x16x32_bf16(aR[mi][1], bR[nh][ni][1], acc[(mh)*4+mi][(nh)*2+ni],0,0,0); } }while(0)

  STG_A(smA, 0, 0);
  STG_B(smB, 0, 0);
  STG_B(smB, 1, 0);
  STG_A(smA, 1, 0);
  VMC4;
  BAR; SCHED0;

  for (int j=0; j<NTALL; ++j) {
    const int p = j & 1;
    const u16* As = smA + (p<<14);
    const u16* Bs = smB + (p<<14);
    u16* Aalt = smA + ((p^1)<<14);
    u16* Balt = smB + ((p^1)<<14);

    LDA_(As, 0); LDB_(Bs, 0);
    STG_A(Aalt, 0, j+1);
    BAR; SCHED0;
    PRIO1; MFMAQ(0,0); PRIO0;
    VMC4;
    BAR; SCHED0;

    LDB_(Bs, 1);
    STG_B(Balt, 0, j+1);
    BAR; SCHED0;
    PRIO1; MFMAQ(0,1); PRIO0;
    VMC4;
    BAR; SCHED0;

    LDA_(As, 1);
    STG_B(Balt, 1, j+1);
    BAR; SCHED0;
    PRIO1; MFMAQ(1,0); PRIO0;
    BAR; SCHED0;

    STG_A(Aalt, 1, j+1);
    BAR; SCHED0;
    PRIO1; MFMAQ(1,1); PRIO0;
    VMC4;
    BAR; SCHED0;
  }
  VMC0;

  if constexpr (V==1) {
    #pragma unroll
    for (int n=0; n<4; ++n) {
      const int col = n0 + wc*64 + (n>>1)*32 + (n&1)*16 + (lane&15);
      const float s = sb[col], bb = sb[512+col];
      float cs = 0.f;
      #pragma unroll
      for (int a=0; a<8; ++a) {
        #pragma unroll
        for (int j2=0; j2<4; ++j2) {
          float v = acc[a][n][j2]*s + bb;
          cs += (v > 0.f) ? v : 0.f;
        }
      }
      cs += __shfl_xor(cs, 16);
      cs += __shfl_xor(cs, 32);
      if (lane < 16) atomicAdd(&en[b*512 + col], cs * (1.0f/4096.0f));
    }
  } else {
    #pragma unroll
    for (int n=0; n<4; ++n) {
      const int col = n0 + wc*64 + (n>>1)*32 + (n&1)*16 + (lane&15);
      const float s = sb[col], bb = sb[512+col];
      #pragma unroll
      for (int a=0; a<8; ++a) {
        const int row0 = ij0 + wr*128 + (a>>2)*64 + (a&3)*16 + ((lane>>4)<<2);
        #pragma unroll
        for (int j2=0; j2<4; ++j2) {
          const size_t idx = ((size_t)(b*4096 + row0 + j2))*512 + col;
          float v = acc[a][n][j2]*s + bb;
          O[idx] = f2bf(v > 0.f ? v : 0.f);
        }
      }
    }
  }
#undef STG_A
#undef STG_B
#undef LDA_
#undef LDB_
#undef MFMAQ
}

// ---------------------------------------------------------------------------
// 128x128 tile GEMM (V2 only): t1 K=128, B per-batch CCT; epi O = feat*(1+acc).
// ---------------------------------------------------------------------------
template<int V>
__global__ __launch_bounds__(256)
void gemm128(const u16* __restrict__ A, const u16* __restrict__ Bw, u16* __restrict__ O,
             const u16* __restrict__ feat, const u16* __restrict__ B2,
             const float* __restrict__ sb, float* __restrict__ en)
{
  constexpr int KSEG = 128;
  __shared__ u16 smA[128*64];
  __shared__ u16 smB[128*64];
  const int tid = threadIdx.x;
  const int lane = tid & 63;
  const int wv = tid >> 6;
  const int wr = wv >> 1, wc = wv & 1;
  const int mt = blockIdx.x, nt = blockIdx.y, b = blockIdx.z;
  const int ij0 = mt*128, n0 = nt*128;
  const int srow = tid >> 3, schunk = tid & 7;

  f32x4 acc[4][4];
  #pragma unroll
  for (int i=0;i<4;++i)
    #pragma unroll
    for (int j=0;j<4;++j) acc[i][j] = (f32x4){0.f,0.f,0.f,0.f};

  const u16* Ab = A + (size_t)b*4096*128;
  const u16* Bb = Bw + (size_t)b*512*128;

  for (int kt=0; kt<KSEG/64; ++kt) {
    const int k0 = kt*64;
    #pragma unroll
    for (int i=0;i<4;++i) {
      const int row = i*32 + srow;
      const int sc = schunk ^ (row & 7);
      gload16(Ab + (size_t)(ij0+row)*128 + (k0 + sc*8), &smA[row*64 + schunk*8]);
    }
    #pragma unroll
    for (int i=0;i<4;++i) {
      const int row = i*32 + srow;
      const int sc = schunk ^ (row & 7);
      gload16(Bb + (size_t)(n0+row)*128 + (k0 + sc*8), &smB[row*64 + schunk*8]);
    }
    __syncthreads();
    #pragma unroll
    for (int ks=0; ks<2; ++ks) {
      short8 av[4], bv[4];
      #pragma unroll
      for (int mi=0;mi<4;++mi) {
        const int r = wr*64 + mi*16 + (lane & 15);
        const int ch = (ks*4 + (lane>>4)) ^ (r & 7);
        av[mi] = *(const short8*)&smA[r*64 + ch*8];
      }
      #pragma unroll
      for (int ni=0;ni<4;++ni) {
        const int r = wc*64 + ni*16 + (lane & 15);
        const int ch = (ks*4 + (lane>>4)) ^ (r & 7);
        bv[ni] = *(const short8*)&smB[r*64 + ch*8];
      }
      #pragma unroll
      for (int mi=0;mi<4;++mi)
        #pragma unroll
        for (int ni=0;ni<4;++ni)
          acc[mi][ni] = __builtin_amdgcn_mfma_f32_16x16x32_bf16(av[mi], bv[ni], acc[mi][ni], 0, 0, 0);
    }
    __syncthreads();
  }

  #pragma unroll
  for (int ni=0;ni<4;++ni) {
    const int col = n0 + wc*64 + ni*16 + (lane & 15);
    #pragma unroll
    for (int mi=0;mi<4;++mi) {
      const int row0 = ij0 + wr*64 + mi*16 + ((lane>>4)<<2);
      #pragma unroll
      for (int j=0;j<4;++j) {
        const size_t idx = ((size_t)(b*4096 + row0 + j))*512 + col;
        O[idx] = f2bf(bf2f(feat[idx]) * (1.0f + acc[mi][ni][j]));
      }
    }
  }
}

// ---------------------------------------------------------------------------
// Weight prep + bn fold (coalesced wt-transpose via LDS slab).
// ---------------------------------------------------------------------------
__global__ __launch_bounds__(256)
void prep_weights(const float* __restrict__ fw, const float* __restrict__ encw,
                  const float* __restrict__ fusw, const float* __restrict__ c6aw,
                  const float* g1,const float* b1,const float* m1,const float* v1,
                  const float* g2,const float* b2,const float* m2,const float* v2,
                  const float* g3,const float* b3,const float* m3,const float* v3,
                  const float* g4,const float* b4,const float* m4,const float* v4,
                  u16* __restrict__ wt, u16* __restrict__ encb,
                  u16* __restrict__ fusb, u16* __restrict__ c6a1,
                  float* __restrict__ bnsb)
{
  const int bx = blockIdx.x, t = threadIdx.x;
  if (bx < 512) {
    __shared__ float slab[2048*9];
    const int o = bx;
    const float4* src4 = (const float4*)(fw + (size_t)o*2048*9);
    float4* slab4 = (float4*)slab;
    #pragma unroll
    for (int i=0; i<18; ++i) slab4[i*256 + t] = src4[i*256 + t];
    __syncthreads();
    #pragma unroll
    for (int tt=0; tt<9; ++tt) {
      #pragma unroll
      for (int i=0; i<8; ++i) {
        const int c = i*256 + t;
        wt[((size_t)o*9 + tt)*2048 + c] = f2bf(slab[c*9 + tt]);
      }
    }
  } else if (bx < 1536) {
    const int i = (bx-512)*256 + t;
    encb[i] = f2bf(encw[i]);
  } else if (bx < 2560) {
    const int i = (bx-1536)*256 + t;
    fusb[i] = f2bf(fusw[i]);
  } else if (bx < 3584) {
    const int i = (bx-2560)*256 + t;
    c6a1[i] = f2bf(c6aw[(size_t)(i>>9)*1024 + (i&511)]);
  } else {
    const int c = (bx-3584)*256 + t;
    if (c < 512) {
      const float eps = 1e-5f;
      float s1 = g1[c]*rsqrtf(v1[c]+eps); bnsb[c]      = s1; bnsb[512+c]  = b1[c]-m1[c]*s1;
      float s2 = g2[c]*rsqrtf(v2[c]+eps); bnsb[1024+c] = s2; bnsb[1536+c] = b2[c]-m2[c]*s2;
      float s3 = g3[c]*rsqrtf(v3[c]+eps); bnsb[2048+c] = s3; bnsb[2560+c] = b3[c]-m3[c]*s3;
      float s4 = g4[c]*rsqrtf(v4[c]+eps); bnsb[3072+c] = s4; bnsb[3584+c] = b4[c]-m4[c]*s4;
    }
  }
}

// x [8][2048][64][64] f32 -> xp [8][66][66][2048] bf16 (zero pad).
// float4 reads; TRANSPOSED LDS tile [px][cl] (stride 260) -> u64 global
// stores (4 ch/lane, 512B/wave/inst; old scalar u16 = 128B/wave/inst).
__global__ __launch_bounds__(256)
void pad_x(const float* __restrict__ x, u16* __restrict__ xp)
{
  __shared__ u16 tileT[64*260];
  const int bx = blockIdx.x;
  const int cb = bx & 7, y = (bx>>3) & 63, b = bx >> 9;
  const int t = threadIdx.x;
  const int xg = t & 15, crow = t >> 4;
  for (int it=0; it<16; ++it) {
    const int cl = it*16 + crow;
    const float4 v = *(const float4*)&x[(((size_t)b*2048 + cb*256 + cl)*64 + y)*64 + xg*4];
    tileT[(xg*4+0)*260 + cl] = f2bf(v.x);
    tileT[(xg*4+1)*260 + cl] = f2bf(v.y);
    tileT[(xg*4+2)*260 + cl] = f2bf(v.z);
    tileT[(xg*4+3)*260 + cl] = f2bf(v.w);
  }
  __syncthreads();
  const size_t rowbase = (size_t)(b*66 + y + 1)*66;
  const int cgrp = t & 63, pg = t >> 6;
  for (int it=0; it<16; ++it) {
    const int px = it*4 + pg;
    const u64 v = *(const u64*)&tileT[px*260 + cgrp*4];
    *(u64*)&xp[(rowbase + px + 1)*2048 + cb*256 + cgrp*4] = v;
  }
  // zero pads (columns 0 and 65 of this row; full rows 0 and 65 when y edge)
  if (pg == 0) {
    *(u64*)&xp[rowbase*2048 + cb*256 + cgrp*4] = 0;
    *(u64*)&xp[(rowbase + 65)*2048 + cb*256 + cgrp*4] = 0;
  }
  if (y == 0) {
    const size_t rb = (size_t)(b*66)*66;
    for (int px=pg; px<66; px+=4)
      *(u64*)&xp[(rb+px)*2048 + cb*256 + cgrp*4] = 0;
  }
  if (y == 63) {
    const size_t rb = (size_t)(b*66 + 65)*66;
    for (int px=pg; px<66; px+=4)
      *(u64*)&xp[(rb+px)*2048 + cb*256 + cgrp*4] = 0;
  }
}

// gamma (8 blk), HH/WW (128 blk), CCT (512 blk x 128 o)
__global__ __launch_bounds__(256)
void small1(const float* __restrict__ en, const float* __restrict__ fcw, const float* __restrict__ fcb,
            const float* __restrict__ w1, const float* __restrict__ Cvec,
            const float* __restrict__ w2, const float* __restrict__ w3,
            const float* __restrict__ Hvec, const float* __restrict__ Wvec,
            float* __restrict__ gamma, u16* __restrict__ CCT,
            float* __restrict__ HH, float* __restrict__ WW)
{
  const int bx = blockIdx.x, t = threadIdx.x;
  if (bx < 8) {
    __shared__ float enl[512];
    const int b = bx;
    for (int c=t;c<512;c+=256) enl[c] = en[b*512+c];
    __syncthreads();
    for (int o=t;o<512;o+=256) {
      float a = fcb[o];
      const float* wr = fcw + (size_t)o*512;
      for (int c=0;c<512;++c) a += enl[c]*wr[c];
      gamma[b*512+o] = 1.0f/(1.0f+__expf(-a));
    }
  } else if (bx < 136) {
    __shared__ float hl[512], wl[512];
    const int r = bx - 8;
    for (int i=t;i<512;i+=256){ hl[i]=Hvec[i]; wl[i]=Wvec[i]; }
    __syncthreads();
    const int i = t & 63, bh = t >> 6;
    for (int bb=bh; bb<8; bb+=4) {
      float sh=0.f, sw=0.f;
      const float* w2r = w2 + ((size_t)r*64 + i)*64;
      const float* w3r = w3 + ((size_t)r*64 + i)*64;
      #pragma unroll 8
      for (int h=0;h<64;++h){ sh += w2r[h]*hl[bb*64+h]; sw += w3r[h]*wl[bb*64+h]; }
      HH[((size_t)bb*128 + r)*64 + i] = 1.0f/(1.0f+__expf(-sh));
      WW[((size_t)bb*128 + r)*64 + i] = 1.0f/(1.0f+__expf(-sw));
    }
  } else {
    __shared__ float cv[4096];
    for (int i=t;i<4096;i+=256) cv[i] = Cvec[i];
    __syncthreads();
    const int rr    = (bx-136) >> 2;           // r in [0,128)
    const int obase = ((bx-136) & 3) * 128;    // o quarter
    const int lane = t & 63, wg = t >> 6;
    const float* w1r = w1 + (size_t)rr*512*512;
    for (int i=0; i<32; ++i) {
      const int o = obase + wg*32 + i;
      const float* row = w1r + (size_t)o*512;
      const float4 wA = *(const float4*)(row + lane*8);
      const float4 wB = *(const float4*)(row + lane*8 + 4);
      float ab[8];
      #pragma unroll
      for (int bb=0;bb<8;++bb) {
        const float4 cA = *(const float4*)&cv[bb*512 + lane*8];
        const float4 cB = *(const float4*)&cv[bb*512 + lane*8 + 4];
        ab[bb] = wA.x*cA.x + wA.y*cA.y + wA.z*cA.z + wA.w*cA.w
               + wB.x*cB.x + wB.y*cB.y + wB.z*cB.z + wB.w*cB.w;
      }
      #pragma unroll
      for (int off=32; off; off>>=1)
        #pragma unroll
        for (int bb=0;bb<8;++bb) ab[bb] += __shfl_xor(ab[bb], off);
      #pragma unroll
      for (int bb=0;bb<8;++bb)
        if (lane == bb)
          CCT[((size_t)bb*512 + o)*128 + rr] = f2bf((1.0f/(1.0f+__expf(-ab[bb]))) * 0.015625f);
    }
  }
}

// w2b[b][o][c] = c6a_w[o][512+c]*(1+gamma[b][c]) bf16 ; HWT[b][ij][r] = HH[b][r][y]*WW[b][r][x]
__global__ __launch_bounds__(256)
void small2(const float* __restrict__ c6aw, const float* __restrict__ gamma,
            const float* __restrict__ HH, const float* __restrict__ WW,
            u16* __restrict__ w2b, u16* __restrict__ HWT)
{
  const int bx = blockIdx.x, t = threadIdx.x;
  if (bx < 4096) {
    const int b = bx >> 9, o = bx & 511;
    const float* src = c6aw + (size_t)o*1024 + 512;
    const float* gmv = gamma + b*512;
    u16* dst = w2b + ((size_t)b*512 + o)*512;
    for (int c=t;c<512;c+=256) dst[c] = f2bf(src[c]*(1.0f+gmv[c]));
  } else {
    __shared__ float wwl[64*129];
    __shared__ float hhy[128];
    const int idx = bx - 4096;
    const int b = idx >> 6, y = idx & 63;
    for (int g=t; g<8192; g+=256){ const int r=g>>6, xx=g&63; wwl[xx*129+r] = WW[((size_t)b*128+r)*64+xx]; }
    if (t < 128) hhy[t] = HH[((size_t)b*128 + t)*64 + y];
    __syncthreads();
    const int r2 = (t & 63)*2, xg = t >> 6;
    for (int xx=xg; xx<64; xx+=4) {
      const float v0 = hhy[r2]   * wwl[xx*129 + r2];
      const float v1 = hhy[r2+1] * wwl[xx*129 + r2 + 1];
      const u32 pk = (u32)f2bf(v0) | ((u32)f2bf(v1)<<16);
      *(u32*)&HWT[((size_t)(b*4096 + y*64 + xx))*128 + r2] = pk;
    }
  }
}

// out[b][o][ij] = sum_c c6b_w[o][c]*h6[b][ij][c] + c6b_b[o]; 2-way c-split.
__global__ __launch_bounds__(256)
void c6b_head(const u16* __restrict__ h6, const float* __restrict__ w,
              const float* __restrict__ bias, float* __restrict__ out)
{
  __shared__ float part[128*21];
  const int t = threadIdx.x;
  const int pl = t & 127, half = t >> 7;
  const int pix = (blockIdx.x << 7) + pl;
  const int b = pix >> 12, ij = pix & 4095;
  float acc[19];
  #pragma unroll
  for (int o=0;o<19;++o) acc[o] = 0.f;
  const u16* hp = h6 + (size_t)pix*512 + half*256;
  const float* wh = w + half*256;
  for (int c0=0;c0<256;c0+=8) {
    const uint4 d = *(const uint4*)(hp + c0);
    const float f0=lo16(d.x),f1=hi16(d.x),f2=lo16(d.y),f3=hi16(d.y),
                f4=lo16(d.z),f5=hi16(d.z),f6=lo16(d.w),f7=hi16(d.w);
    #pragma unroll
    for (int o=0;o<19;++o) {
      const float* wr = wh + o*512 + c0;
      acc[o] += f0*wr[0] + f1*wr[1] + f2*wr[2] + f3*wr[3]
              + f4*wr[4] + f5*wr[5] + f6*wr[6] + f7*wr[7];
    }
  }
  if (half) {
    #pragma unroll
    for (int o=0;o<19;++o) part[pl*21 + o] = acc[o];
  }
  __syncthreads();
  if (!half) {
    #pragma unroll
    for (int o=0;o<19;++o)
      out[((size_t)(b*19 + o))*4096 + ij] = acc[o] + part[pl*21 + o] + bias[o];
  }
}

// ---------------------------------------------------------------------------
extern "C" void kernel_launch(void* const* d_in, const int* in_sizes, int n_in,
                              void* d_out, int out_size, void* d_ws, size_t ws_size,
                              hipStream_t stream)
{
  (void)in_sizes; (void)n_in; (void)out_size;
  const float* x     = (const float*)d_in[0];
  const float* fw    = (const float*)d_in[1];
  const float* bnp[16];
  for (int i=0;i<16;++i) bnp[i] = (const float*)d_in[2+i];
  const float* enc_w = (const float*)d_in[18];
  const float* fc_w  = (const float*)d_in[19];
  const float* fc_b  = (const float*)d_in[20];
  const float* w1    = (const float*)d_in[21];
  const float* w2    = (const float*)d_in[22];
  const float* w3    = (const float*)d_in[23];
  const float* fus_w = (const float*)d_in[24];
  const float* c6a_w = (const float*)d_in[25];
  const float* c6b_w = (const float*)d_in[26];
  const float* c6b_b = (const float*)d_in[27];

  char* ws = (char*)d_ws;
  constexpr size_t OFF_XP=0, OFF_T=0, OFF_OUTS=33554432ull, OFF_H6=67108864ull,
    OFF_WT=142737408ull, OFF_FEAT=161611776ull, OFF_HWT=195166208ull, OFF_W2B=203554816ull,
    OFF_CCT=207749120ull, OFF_ENCB=208797696ull, OFF_FUSB=209321984ull, OFF_C6A1=209846272ull,
    OFF_HH=210370560ull, OFF_WW=210632704ull, OFF_EN=210894848ull, OFF_CV=210911232ull,
    OFF_HV=210927616ull, OFF_WV=210929664ull, OFF_GAMMA=210931712ull, OFF_BNSB=210948096ull,
    NEEDED=210964480ull;
  if (ws_size < NEEDED) return;

  u16* xp    = (u16*)(ws + OFF_XP);
  u16* tb    = (u16*)(ws + OFF_T);
  u16* outs  = (u16*)(ws + OFF_OUTS);
  u16* h6    = (u16*)(ws + OFF_H6);
  u16* wt    = (u16*)(ws + OFF_WT);
  u16* featb = (u16*)(ws + OFF_FEAT);
  u16* hwt   = (u16*)(ws + OFF_HWT);
  u16* w2b   = (u16*)(ws + OFF_W2B);
  u16* cct   = (u16*)(ws + OFF_CCT);
  u16* encb  = (u16*)(ws + OFF_ENCB);
  u16* fusb  = (u16*)(ws + OFF_FUSB);
  u16* c6a1  = (u16*)(ws + OFF_C6A1);
  float* HH  = (float*)(ws + OFF_HH);
  float* WW  = (float*)(ws + OFF_WW);
  float* en  = (float*)(ws + OFF_EN);
  float* Cv  = (float*)(ws + OFF_CV);
  float* Hv  = (float*)(ws + OFF_HV);
  float* Wv  = (float*)(ws + OFF_WV);
  float* gm  = (float*)(ws + OFF_GAMMA);
  float* bnsb= (float*)(ws + OFF_BNSB);

  hipMemsetAsync(ws + OFF_EN, 0, 36864, stream);

  prep_weights<<<3586,256,0,stream>>>(fw, enc_w, fus_w, c6a_w,
      bnp[0],bnp[1],bnp[2],bnp[3], bnp[4],bnp[5],bnp[6],bnp[7],
      bnp[8],bnp[9],bnp[10],bnp[11], bnp[12],bnp[13],bnp[14],bnp[15],
      wt, encb, fusb, c6a1, bnsb);
  pad_x<<<4096,256,0,stream>>>(x, xp);
  conv_gemm256<<<dim3(16,2,8),512,0,stream>>>(xp, wt, featb, bnsb, Cv, Hv, Wv);
  gemm256<1><<<dim3(16,2,8),512,0,stream>>>(featb, nullptr, encb, nullptr, nullptr, bnsb+1024, en);
  small1<<<648,256,0,stream>>>(en, fc_w, fc_b, w1, Cv, w2, w3, Hv, Wv, gm, cct, HH, WW);
  small2<<<4608,256,0,stream>>>(c6a_w, gm, HH, WW, w2b, hwt);
  gemm128<2><<<dim3(32,4,8),256,0,stream>>>(hwt, cct, tb, featb, nullptr, nullptr, nullptr);
  gemm256<3><<<dim3(16,2,8),512,0,stream>>>(tb, nullptr, fusb, nullptr, outs, bnsb+2048, nullptr);
  gemm256<4><<<dim3(16,2,8),512,0,stream>>>(outs, featb, c6a1, w2b, h6, bnsb+3072, nullptr);
  c6b_head<<<256,256,0,stream>>>(h6, c6b_w, c6b_b, (float*)d_out);
}